// Round 1
// baseline (377.842 us; speedup 1.0000x reference)
//
#include <hip/hip_runtime.h>
#include <cstdint>
#include <cstddef>

typedef unsigned short u16;
typedef __attribute__((ext_vector_type(8))) short bf16x8;   // 8 bf16 = 4 VGPRs
typedef __attribute__((ext_vector_type(4))) float f32x4;

__device__ __forceinline__ u16 f2bf(float f) {
  unsigned u = __builtin_bit_cast(unsigned, f);
  return (u16)((u + 0x7FFFu + ((u >> 16) & 1u)) >> 16);   // RNE
}

__device__ __forceinline__ void gload_lds16(const void* g, void* l) {
  __builtin_amdgcn_global_load_lds(
      (const __attribute__((address_space(1))) void*)g,
      (__attribute__((address_space(3))) void*)l,
      16, 0, 0);
}

// ---------------- cast fp32 -> bf16 ----------------
__global__ void cast_bf16_kernel(const float* __restrict__ in, u16* __restrict__ out, int n4) {
  int i = blockIdx.x * blockDim.x + threadIdx.x;
  int stride = gridDim.x * blockDim.x;
  for (int idx = i; idx < n4; idx += stride) {
    float4 f = ((const float4*)in)[idx];
    ushort4 o = make_ushort4(f2bf(f.x), f2bf(f.y), f2bf(f.z), f2bf(f.w));
    ((ushort4*)out)[idx] = o;
  }
}

// ---------------- NT GEMM: out[m][n] = sum_k A[m][k]*W[n][k] + bias[n] ----------------
// A: M x 1024 bf16 row-major. W: 1024 x 1024 bf16 row-major (N x K).
// MODE 0: bf16 out row-major (ldc=1024)          (Q, K)
// MODE 1: bf16 out V-transposed (B,H,dk,S)       (V)
// MODE 2: f32  out row-major                     (final output)
template <int MODE>
__global__ __launch_bounds__(256, 2)
void gemm_bt(const u16* __restrict__ A, const u16* __restrict__ W,
             const float* __restrict__ bias, void* __restrict__ outp) {
  __shared__ u16 Alds[128 * 32];
  __shared__ u16 Blds[128 * 32];
  const int tid  = threadIdx.x;
  const int lane = tid & 63;
  const int wid  = tid >> 6;
  const int m0 = blockIdx.y * 128;
  const int n0 = blockIdx.x * 128;
  const int wm = (wid >> 1) * 64;
  const int wn = (wid & 1) * 64;

  f32x4 acc[4][4] = {};

  const int srow = tid >> 2;          // 0..63
  const int scol = (tid & 3) * 8;     // k-offset (elements)
  const u16* Ag = A + (size_t)(m0 + srow) * 1024 + scol;
  const u16* Wg = W + (size_t)(n0 + srow) * 1024 + scol;
  u16* Al = &Alds[wid * 16 * 32];     // wave-uniform LDS dest
  u16* Bl = &Blds[wid * 16 * 32];

  for (int k0 = 0; k0 < 1024; k0 += 32) {
    __syncthreads();
    gload_lds16(Ag + k0,             Al);
    gload_lds16(Ag + 64 * 1024 + k0, Al + 64 * 32);
    gload_lds16(Wg + k0,             Bl);
    gload_lds16(Wg + 64 * 1024 + k0, Bl + 64 * 32);
    __syncthreads();
    bf16x8 a[4], bb[4];
#pragma unroll
    for (int i = 0; i < 4; ++i)
      a[i] = *(const bf16x8*)&Alds[(wm + i * 16 + (lane & 15)) * 32 + (lane >> 4) * 8];
#pragma unroll
    for (int i = 0; i < 4; ++i)
      bb[i] = *(const bf16x8*)&Blds[(wn + i * 16 + (lane & 15)) * 32 + (lane >> 4) * 8];
#pragma unroll
    for (int mi = 0; mi < 4; ++mi)
#pragma unroll
      for (int ni = 0; ni < 4; ++ni)
        acc[mi][ni] = __builtin_amdgcn_mfma_f32_16x16x32_bf16(a[mi], bb[ni], acc[mi][ni], 0, 0, 0);
  }

  // epilogue: C/D layout col=lane&15, row=(lane>>4)*4+r
#pragma unroll
  for (int ni = 0; ni < 4; ++ni) {
    const int n = n0 + wn + ni * 16 + (lane & 15);
    const float bv = bias[n];
#pragma unroll
    for (int mi = 0; mi < 4; ++mi) {
      const int mBase = m0 + wm + mi * 16 + ((lane >> 4) << 2);
      if (MODE == 0) {
        u16* o = (u16*)outp;
#pragma unroll
        for (int r = 0; r < 4; ++r)
          o[(size_t)(mBase + r) * 1024 + n] = f2bf(acc[mi][ni][r] + bv);
      } else if (MODE == 2) {
        float* o = (float*)outp;
#pragma unroll
        for (int r = 0; r < 4; ++r)
          o[(size_t)(mBase + r) * 1024 + n] = acc[mi][ni][r] + bv;
      } else {
        // V transposed: vt[((batch*16 + h)*64 + d)*512 + s], s = m%512 (4 consecutive)
        u16* o = (u16*)outp;
        const int batch = mBase >> 9;
        const int s = mBase & 511;
        const int h = n >> 6;
        const int d = n & 63;
        ushort4 ov = make_ushort4(f2bf(acc[mi][ni][0] + bv), f2bf(acc[mi][ni][1] + bv),
                                  f2bf(acc[mi][ni][2] + bv), f2bf(acc[mi][ni][3] + bv));
        *(ushort4*)&o[((size_t)((batch * 16 + h) * 64 + d) << 9) + s] = ov;
      }
    }
  }
}

// ---------------- attention: one block per (b,h,qblock of 32 rows) ----------------
// Q,K: (B,S,D) bf16 ; Vt: (B,H,dk,S) bf16 ; rel: (1023,16) f32 ; Oa: (B,S,D) bf16
__global__ __launch_bounds__(256, 1)
void attn_kernel(const u16* __restrict__ Q, const u16* __restrict__ K,
                 const u16* __restrict__ Vt, const float* __restrict__ rel,
                 u16* __restrict__ Oa) {
  __shared__ float Sblk[32 * 528];
  __shared__ u16   P[32 * 520];
  __shared__ float tcol[544];
  __shared__ float rowsum[32];

  const int tid  = threadIdx.x;
  const int lane = tid & 63;
  const int wid  = tid >> 6;
  const int blk  = blockIdx.x;
  const int qb   = blk & 15;
  const int bh   = blk >> 4;
  const int h    = bh & 15;
  const int batch = bh >> 4;
  const int q0   = qb * 32;

  // stage rel_table column h for this q-block: idx in [q0, q0+542]
  for (int u = tid; u < 543; u += 256)
    tcol[u] = rel[(q0 + u) * 16 + h];

  // Q fragments (rows q0..q0+31), kept in registers
  const size_t xbase = ((size_t)batch * 512) * 1024 + (size_t)h * 64;
  bf16x8 aq[2][2];
#pragma unroll
  for (int mi = 0; mi < 2; ++mi)
#pragma unroll
    for (int ks = 0; ks < 2; ++ks)
      aq[mi][ks] = *(const bf16x8*)&Q[xbase + (size_t)(q0 + mi * 16 + (lane & 15)) * 1024 +
                                      ks * 32 + (lane >> 4) * 8];

  // QK^T: wave w covers key cols [w*128, w*128+128)
  const int wcol = wid * 128;
  f32x4 acc[2][8] = {};
#pragma unroll
  for (int f = 0; f < 8; ++f) {
#pragma unroll
    for (int ks = 0; ks < 2; ++ks) {
      bf16x8 bk = *(const bf16x8*)&K[xbase + (size_t)(wcol + f * 16 + (lane & 15)) * 1024 +
                                     ks * 32 + (lane >> 4) * 8];
#pragma unroll
      for (int mi = 0; mi < 2; ++mi)
        acc[mi][f] = __builtin_amdgcn_mfma_f32_16x16x32_bf16(aq[mi][ks], bk, acc[mi][f], 0, 0, 0);
    }
  }
  __syncthreads();  // tcol ready

  const float scale = 0.125f;  // 1/sqrt(64)
#pragma unroll
  for (int mi = 0; mi < 2; ++mi) {
#pragma unroll
    for (int f = 0; f < 8; ++f) {
      const int col  = wcol + f * 16 + (lane & 15);
      const int rowb = mi * 16 + ((lane >> 4) << 2);
#pragma unroll
      for (int r = 0; r < 4; ++r) {
        const int row = rowb + r;
        Sblk[row * 528 + col] = acc[mi][f][r] * scale + tcol[row - col + 511];
      }
    }
  }
  __syncthreads();

  // softmax: row = tid>>3 ; 8 threads/row, strided float4 chunks
  {
    const int row = tid >> 3;
    const int c8  = tid & 7;
    const float* rowp = &Sblk[row * 528];
    float mx = -1e30f;
#pragma unroll
    for (int i = 0; i < 16; ++i) {
      const float4 v = *(const float4*)&rowp[c8 * 4 + i * 32];
      mx = fmaxf(mx, fmaxf(fmaxf(v.x, v.y), fmaxf(v.z, v.w)));
    }
    mx = fmaxf(mx, __shfl_xor(mx, 1));
    mx = fmaxf(mx, __shfl_xor(mx, 2));
    mx = fmaxf(mx, __shfl_xor(mx, 4));
    float sum = 0.f;
#pragma unroll
    for (int i = 0; i < 16; ++i) {
      const float4 v = *(const float4*)&rowp[c8 * 4 + i * 32];
      const float e0 = __expf(v.x - mx);
      const float e1 = __expf(v.y - mx);
      const float e2 = __expf(v.z - mx);
      const float e3 = __expf(v.w - mx);
      sum += (e0 + e1) + (e2 + e3);
      *(ushort4*)&P[row * 520 + c8 * 4 + i * 32] =
          make_ushort4(f2bf(e0), f2bf(e1), f2bf(e2), f2bf(e3));
    }
    sum += __shfl_xor(sum, 1);
    sum += __shfl_xor(sum, 2);
    sum += __shfl_xor(sum, 4);
    if (c8 == 0) rowsum[row] = sum;
  }
  __syncthreads();

  // PV: wave w -> dk block d0 = w*16 ; K-dim = 512 keys = 16 steps
  const int d0 = wid * 16;
  const size_t vtbase = ((size_t)(batch * 16 + h) * 64) * 512;
  f32x4 acc2[2][2] = {};
#pragma unroll
  for (int ks = 0; ks < 16; ++ks) {
    bf16x8 bv = *(const bf16x8*)&Vt[vtbase + (size_t)(d0 + (lane & 15)) * 512 +
                                    ks * 32 + (lane >> 4) * 8];
#pragma unroll
    for (int mi = 0; mi < 2; ++mi) {
      bf16x8 ap = *(const bf16x8*)&P[(mi * 16 + (lane & 15)) * 520 + ks * 32 + (lane >> 4) * 8];
      acc2[mi][ks & 1] = __builtin_amdgcn_mfma_f32_16x16x32_bf16(ap, bv, acc2[mi][ks & 1], 0, 0, 0);
    }
  }

#pragma unroll
  for (int mi = 0; mi < 2; ++mi) {
    const int rowb = mi * 16 + ((lane >> 4) << 2);
#pragma unroll
    for (int r = 0; r < 4; ++r) {
      const int row = rowb + r;
      const float v = (acc2[mi][0][r] + acc2[mi][1][r]) / rowsum[row];
      Oa[((size_t)batch * 512 + q0 + row) * 1024 + h * 64 + d0 + (lane & 15)] = f2bf(v);
    }
  }
}

// ---------------- launch ----------------
extern "C" void kernel_launch(void* const* d_in, const int* in_sizes, int n_in,
                              void* d_out, int out_size, void* d_ws, size_t ws_size,
                              hipStream_t stream) {
  (void)in_sizes; (void)n_in; (void)out_size; (void)ws_size;
  const float* x   = (const float*)d_in[0];
  const float* Wq  = (const float*)d_in[1];
  const float* bq  = (const float*)d_in[2];
  const float* Wk  = (const float*)d_in[3];
  const float* bk  = (const float*)d_in[4];
  const float* Wv  = (const float*)d_in[5];
  const float* bv  = (const float*)d_in[6];
  const float* Wo  = (const float*)d_in[7];
  const float* bo  = (const float*)d_in[8];
  const float* rel = (const float*)d_in[9];
  float* out = (float*)d_out;

  u16* p = (u16*)d_ws;
  u16* xbf = p;  p += (size_t)8192 * 1024;
  u16* wqb = p;  p += (size_t)1024 * 1024;
  u16* wkb = p;  p += (size_t)1024 * 1024;
  u16* wvb = p;  p += (size_t)1024 * 1024;
  u16* wob = p;  p += (size_t)1024 * 1024;
  u16* qbf = p;  p += (size_t)8192 * 1024;
  u16* kbf = p;  p += (size_t)8192 * 1024;
  u16* vtb = p;  p += (size_t)8192 * 1024;
  u16* abf = p;  p += (size_t)8192 * 1024;

  cast_bf16_kernel<<<1024, 256, 0, stream>>>(x,  xbf, 8192 * 1024 / 4);
  cast_bf16_kernel<<<256,  256, 0, stream>>>(Wq, wqb, 1024 * 1024 / 4);
  cast_bf16_kernel<<<256,  256, 0, stream>>>(Wk, wkb, 1024 * 1024 / 4);
  cast_bf16_kernel<<<256,  256, 0, stream>>>(Wv, wvb, 1024 * 1024 / 4);
  cast_bf16_kernel<<<256,  256, 0, stream>>>(Wo, wob, 1024 * 1024 / 4);

  dim3 grid(8, 64);  // n-tiles x m-tiles
  gemm_bt<0><<<grid, 256, 0, stream>>>(xbf, wqb, bq, qbf);
  gemm_bt<0><<<grid, 256, 0, stream>>>(xbf, wkb, bk, kbf);
  gemm_bt<1><<<grid, 256, 0, stream>>>(xbf, wvb, bv, vtb);

  attn_kernel<<<4096, 256, 0, stream>>>(qbf, kbf, vtb, rel, abf);

  gemm_bt<2><<<grid, 256, 0, stream>>>(abf, wob, bo, out);
}

// Round 2
// 322.517 us; speedup vs baseline: 1.1715x; 1.1715x over previous
//
#include <hip/hip_runtime.h>
#include <cstdint>
#include <cstddef>

typedef unsigned short u16;
typedef __attribute__((ext_vector_type(8))) short bf16x8;   // 8 bf16 = 4 VGPRs
typedef __attribute__((ext_vector_type(4))) float f32x4;

__device__ __forceinline__ u16 f2bf(float f) {
  unsigned u = __builtin_bit_cast(unsigned, f);
  return (u16)((u + 0x7FFFu + ((u >> 16) & 1u)) >> 16);   // RNE
}

__device__ __forceinline__ void gload_lds16(const void* g, void* l) {
  __builtin_amdgcn_global_load_lds(
      (const __attribute__((address_space(1))) void*)g,
      (__attribute__((address_space(3))) void*)l,
      16, 0, 0);
}

// ---------------- cast fp32 -> bf16 ----------------
__global__ void cast_bf16_kernel(const float* __restrict__ in, u16* __restrict__ out, int n4) {
  int i = blockIdx.x * blockDim.x + threadIdx.x;
  int stride = gridDim.x * blockDim.x;
  for (int idx = i; idx < n4; idx += stride) {
    float4 f = ((const float4*)in)[idx];
    ushort4 o = make_ushort4(f2bf(f.x), f2bf(f.y), f2bf(f.z), f2bf(f.w));
    ((ushort4*)out)[idx] = o;
  }
}

// ---------------- NT GEMM: out[m][n] = sum_k A[m][k]*W[n][k] + bias[n] ----------------
// A: M x 1024 bf16 row-major. W: 1024 x 1024 bf16 row-major (N x K).
// MODE 0: bf16 out row-major (ldc=1024)          (Q, K)
// MODE 1: bf16 out V-transposed (B,H,dk,S)       (V)
// MODE 2: f32  out row-major                     (final output)
template <int MODE>
__global__ __launch_bounds__(256, 2)
void gemm_bt(const u16* __restrict__ A, const u16* __restrict__ W,
             const float* __restrict__ bias, void* __restrict__ outp) {
  __shared__ u16 Alds[128 * 32];
  __shared__ u16 Blds[128 * 32];
  const int tid  = threadIdx.x;
  const int lane = tid & 63;
  const int wid  = tid >> 6;
  const int m0 = blockIdx.y * 128;
  const int n0 = blockIdx.x * 128;
  const int wm = (wid >> 1) * 64;
  const int wn = (wid & 1) * 64;

  f32x4 acc[4][4] = {};

  const int srow = tid >> 2;          // 0..63
  const int scol = (tid & 3) * 8;     // k-offset (elements)
  const u16* Ag = A + (size_t)(m0 + srow) * 1024 + scol;
  const u16* Wg = W + (size_t)(n0 + srow) * 1024 + scol;
  u16* Al = &Alds[wid * 16 * 32];     // wave-uniform LDS dest
  u16* Bl = &Blds[wid * 16 * 32];

  for (int k0 = 0; k0 < 1024; k0 += 32) {
    __syncthreads();
    gload_lds16(Ag + k0,             Al);
    gload_lds16(Ag + 64 * 1024 + k0, Al + 64 * 32);
    gload_lds16(Wg + k0,             Bl);
    gload_lds16(Wg + 64 * 1024 + k0, Bl + 64 * 32);
    __syncthreads();
    bf16x8 a[4], bb[4];
#pragma unroll
    for (int i = 0; i < 4; ++i)
      a[i] = *(const bf16x8*)&Alds[(wm + i * 16 + (lane & 15)) * 32 + (lane >> 4) * 8];
#pragma unroll
    for (int i = 0; i < 4; ++i)
      bb[i] = *(const bf16x8*)&Blds[(wn + i * 16 + (lane & 15)) * 32 + (lane >> 4) * 8];
#pragma unroll
    for (int mi = 0; mi < 4; ++mi)
#pragma unroll
      for (int ni = 0; ni < 4; ++ni)
        acc[mi][ni] = __builtin_amdgcn_mfma_f32_16x16x32_bf16(a[mi], bb[ni], acc[mi][ni], 0, 0, 0);
  }

  // epilogue: C/D layout col=lane&15, row=(lane>>4)*4+r
#pragma unroll
  for (int ni = 0; ni < 4; ++ni) {
    const int n = n0 + wn + ni * 16 + (lane & 15);
    const float bv = bias[n];
#pragma unroll
    for (int mi = 0; mi < 4; ++mi) {
      const int mBase = m0 + wm + mi * 16 + ((lane >> 4) << 2);
      if (MODE == 0) {
        u16* o = (u16*)outp;
#pragma unroll
        for (int r = 0; r < 4; ++r)
          o[(size_t)(mBase + r) * 1024 + n] = f2bf(acc[mi][ni][r] + bv);
      } else if (MODE == 2) {
        float* o = (float*)outp;
#pragma unroll
        for (int r = 0; r < 4; ++r)
          o[(size_t)(mBase + r) * 1024 + n] = acc[mi][ni][r] + bv;
      } else {
        // V transposed: vt[((batch*16 + h)*64 + d)*512 + s], s = m%512 (4 consecutive)
        u16* o = (u16*)outp;
        const int batch = mBase >> 9;
        const int s = mBase & 511;
        const int h = n >> 6;
        const int d = n & 63;
        ushort4 ov = make_ushort4(f2bf(acc[mi][ni][0] + bv), f2bf(acc[mi][ni][1] + bv),
                                  f2bf(acc[mi][ni][2] + bv), f2bf(acc[mi][ni][3] + bv));
        *(ushort4*)&o[((size_t)((batch * 16 + h) * 64 + d) << 9) + s] = ov;
      }
    }
  }
}

// ---------------- attention: one block per (b,h,qblock of 32 rows) ----------------
// Q,K: (B,S,D) bf16 ; Vt: (B,H,dk,S) bf16 ; rel: (1023,16) f32 ; Oa: (B,S,D) bf16
// Softmax is done from MFMA accumulator registers; only P (bf16) lives in LDS.
__global__ __launch_bounds__(256, 4)
void attn_kernel(const u16* __restrict__ Q, const u16* __restrict__ K,
                 const u16* __restrict__ Vt, const float* __restrict__ rel,
                 u16* __restrict__ Oa) {
  __shared__ u16   P[32 * 520];      // 33.3 KB probs (bf16)
  __shared__ float tcol[544];        // rel-bias column for this q-block
  __shared__ float wredA[4][32];     // cross-wave row max
  __shared__ float wredB[4][32];     // cross-wave row sum

  const int tid  = threadIdx.x;
  const int lane = tid & 63;
  const int wid  = tid >> 6;
  const int blk  = blockIdx.x;
  const int qb   = blk & 15;
  const int bh   = blk >> 4;
  const int h    = bh & 15;
  const int batch = bh >> 4;
  const int q0   = qb * 32;

  const int lc = lane & 15;          // column-within-16 / q-row for A frags
  const int lr = (lane >> 4) << 2;   // row base (0,4,8,12) in C/D layout

  // stage rel_table column h: bias(row,col) = tcol[row - col + 511], idx in [0,542]
  for (int u = tid; u < 543; u += 256)
    tcol[u] = rel[(q0 + u) * 16 + h];

  // Q fragments (rows q0..q0+31) in registers
  const size_t xbase = ((size_t)batch * 512) * 1024 + (size_t)h * 64;
  bf16x8 aq[2][2];
#pragma unroll
  for (int mi = 0; mi < 2; ++mi)
#pragma unroll
    for (int ks = 0; ks < 2; ++ks)
      aq[mi][ks] = *(const bf16x8*)&Q[xbase + (size_t)(q0 + mi * 16 + lc) * 1024 +
                                      ks * 32 + (lane >> 4) * 8];

  // QK^T: wave w covers key cols [w*128, w*128+128)
  const int wcol = wid * 128;
  f32x4 acc[2][8] = {};
#pragma unroll
  for (int f = 0; f < 8; ++f) {
#pragma unroll
    for (int ks = 0; ks < 2; ++ks) {
      bf16x8 bk = *(const bf16x8*)&K[xbase + (size_t)(wcol + f * 16 + lc) * 1024 +
                                     ks * 32 + (lane >> 4) * 8];
#pragma unroll
      for (int mi = 0; mi < 2; ++mi)
        acc[mi][f] = __builtin_amdgcn_mfma_f32_16x16x32_bf16(aq[mi][ks], bk, acc[mi][f], 0, 0, 0);
    }
  }
  __syncthreads();   // tcol ready

  // scale + rel bias, in registers
  const float scale = 0.125f;  // 1/sqrt(64)
#pragma unroll
  for (int mi = 0; mi < 2; ++mi)
#pragma unroll
    for (int f = 0; f < 8; ++f) {
      const int col = wcol + f * 16 + lc;
#pragma unroll
      for (int r = 0; r < 4; ++r) {
        const int row = mi * 16 + lr + r;
        acc[mi][f][r] = acc[mi][f][r] * scale + tcol[row - col + 511];
      }
    }

  // row max: in-register over f, shfl over the 16-lane col group, LDS across waves
  float rmax[2][4];
#pragma unroll
  for (int mi = 0; mi < 2; ++mi)
#pragma unroll
    for (int r = 0; r < 4; ++r) {
      float m = fmaxf(fmaxf(fmaxf(acc[mi][0][r], acc[mi][1][r]),
                            fmaxf(acc[mi][2][r], acc[mi][3][r])),
                      fmaxf(fmaxf(acc[mi][4][r], acc[mi][5][r]),
                            fmaxf(acc[mi][6][r], acc[mi][7][r])));
      m = fmaxf(m, __shfl_xor(m, 1));
      m = fmaxf(m, __shfl_xor(m, 2));
      m = fmaxf(m, __shfl_xor(m, 4));
      m = fmaxf(m, __shfl_xor(m, 8));
      rmax[mi][r] = m;
      if (lc == 0) wredA[wid][mi * 16 + lr + r] = m;
    }
  __syncthreads();
#pragma unroll
  for (int mi = 0; mi < 2; ++mi)
#pragma unroll
    for (int r = 0; r < 4; ++r) {
      const int row = mi * 16 + lr + r;
      rmax[mi][r] = fmaxf(fmaxf(wredA[0][row], wredA[1][row]),
                          fmaxf(wredA[2][row], wredA[3][row]));
    }

  // exp + P(bf16) write + row sum
  float rsum[2][4] = {};
#pragma unroll
  for (int mi = 0; mi < 2; ++mi)
#pragma unroll
    for (int f = 0; f < 8; ++f) {
      const int col = wcol + f * 16 + lc;
#pragma unroll
      for (int r = 0; r < 4; ++r) {
        const float e = __expf(acc[mi][f][r] - rmax[mi][r]);
        rsum[mi][r] += e;
        P[(mi * 16 + lr + r) * 520 + col] = f2bf(e);
      }
    }
#pragma unroll
  for (int mi = 0; mi < 2; ++mi)
#pragma unroll
    for (int r = 0; r < 4; ++r) {
      float s = rsum[mi][r];
      s += __shfl_xor(s, 1);
      s += __shfl_xor(s, 2);
      s += __shfl_xor(s, 4);
      s += __shfl_xor(s, 8);
      if (lc == 0) wredB[wid][mi * 16 + lr + r] = s;
    }
  __syncthreads();   // P + wredB ready

  // PV: wave w -> dk block d0 = w*16 ; 512 keys = 16 k-steps
  const int d0 = wid * 16;
  const size_t vtbase = ((size_t)(batch * 16 + h) * 64) * 512;
  f32x4 acc2[2][2] = {};
#pragma unroll
  for (int ks = 0; ks < 16; ++ks) {
    bf16x8 bv = *(const bf16x8*)&Vt[vtbase + (size_t)(d0 + lc) * 512 +
                                    ks * 32 + (lane >> 4) * 8];
#pragma unroll
    for (int mi = 0; mi < 2; ++mi) {
      bf16x8 ap = *(const bf16x8*)&P[(mi * 16 + lc) * 520 + ks * 32 + (lane >> 4) * 8];
      acc2[mi][ks & 1] = __builtin_amdgcn_mfma_f32_16x16x32_bf16(ap, bv, acc2[mi][ks & 1], 0, 0, 0);
    }
  }

#pragma unroll
  for (int mi = 0; mi < 2; ++mi) {
#pragma unroll
    for (int r = 0; r < 4; ++r) {
      const int row = mi * 16 + lr + r;
      const float s = (wredB[0][row] + wredB[1][row]) + (wredB[2][row] + wredB[3][row]);
      const float v = (acc2[mi][0][r] + acc2[mi][1][r]) / s;
      Oa[((size_t)batch * 512 + q0 + row) * 1024 + h * 64 + d0 + lc] = f2bf(v);
    }
  }
}

// ---------------- launch ----------------
extern "C" void kernel_launch(void* const* d_in, const int* in_sizes, int n_in,
                              void* d_out, int out_size, void* d_ws, size_t ws_size,
                              hipStream_t stream) {
  (void)in_sizes; (void)n_in; (void)out_size; (void)ws_size;
  const float* x   = (const float*)d_in[0];
  const float* Wq  = (const float*)d_in[1];
  const float* bq  = (const float*)d_in[2];
  const float* Wk  = (const float*)d_in[3];
  const float* bk  = (const float*)d_in[4];
  const float* Wv  = (const float*)d_in[5];
  const float* bv  = (const float*)d_in[6];
  const float* Wo  = (const float*)d_in[7];
  const float* bo  = (const float*)d_in[8];
  const float* rel = (const float*)d_in[9];
  float* out = (float*)d_out;

  u16* p = (u16*)d_ws;
  u16* xbf = p;  p += (size_t)8192 * 1024;
  u16* wqb = p;  p += (size_t)1024 * 1024;
  u16* wkb = p;  p += (size_t)1024 * 1024;
  u16* wvb = p;  p += (size_t)1024 * 1024;
  u16* wob = p;  p += (size_t)1024 * 1024;
  u16* qbf = p;  p += (size_t)8192 * 1024;
  u16* kbf = p;  p += (size_t)8192 * 1024;
  u16* vtb = p;  p += (size_t)8192 * 1024;
  u16* abf = p;  p += (size_t)8192 * 1024;

  cast_bf16_kernel<<<1024, 256, 0, stream>>>(x,  xbf, 8192 * 1024 / 4);
  cast_bf16_kernel<<<256,  256, 0, stream>>>(Wq, wqb, 1024 * 1024 / 4);
  cast_bf16_kernel<<<256,  256, 0, stream>>>(Wk, wkb, 1024 * 1024 / 4);
  cast_bf16_kernel<<<256,  256, 0, stream>>>(Wv, wvb, 1024 * 1024 / 4);
  cast_bf16_kernel<<<256,  256, 0, stream>>>(Wo, wob, 1024 * 1024 / 4);

  dim3 grid(8, 64);  // n-tiles x m-tiles
  gemm_bt<0><<<grid, 256, 0, stream>>>(xbf, wqb, bq, qbf);
  gemm_bt<0><<<grid, 256, 0, stream>>>(xbf, wkb, bk, kbf);
  gemm_bt<1><<<grid, 256, 0, stream>>>(xbf, wvb, bv, vtb);

  attn_kernel<<<4096, 256, 0, stream>>>(qbf, kbf, vtb, rel, abf);

  gemm_bt<2><<<grid, 256, 0, stream>>>(abf, wob, bo, out);
}

// Round 4
// 259.538 us; speedup vs baseline: 1.4558x; 1.2427x over previous
//
#include <hip/hip_runtime.h>
#include <cstdint>
#include <cstddef>

typedef unsigned short u16;
typedef __attribute__((ext_vector_type(8))) short bf16x8;   // 8 bf16 = 4 VGPRs
typedef __attribute__((ext_vector_type(4))) float f32x4;

__device__ __forceinline__ u16 f2bf(float f) {
  unsigned u = __builtin_bit_cast(unsigned, f);
  return (u16)((u + 0x7FFFu + ((u >> 16) & 1u)) >> 16);   // RNE
}

__device__ __forceinline__ void gload_lds16(const void* g, void* l) {
  __builtin_amdgcn_global_load_lds(
      (const __attribute__((address_space(1))) void*)g,
      (__attribute__((address_space(3))) void*)l,
      16, 0, 0);
}

// ---------------- cast fp32 -> bf16 ----------------
__global__ void cast_bf16_kernel(const float* __restrict__ in, u16* __restrict__ out, int n4) {
  int i = blockIdx.x * blockDim.x + threadIdx.x;
  int stride = gridDim.x * blockDim.x;
  for (int idx = i; idx < n4; idx += stride) {
    float4 f = ((const float4*)in)[idx];
    ushort4 o = make_ushort4(f2bf(f.x), f2bf(f.y), f2bf(f.z), f2bf(f.w));
    ((ushort4*)out)[idx] = o;
  }
}

// merged cast for the four 1024x1024 weights (saves 3 launches)
__global__ void cast_w4_kernel(const float* __restrict__ a, const float* __restrict__ b,
                               const float* __restrict__ c, const float* __restrict__ d,
                               u16* __restrict__ oa, u16* __restrict__ ob,
                               u16* __restrict__ oc, u16* __restrict__ od) {
  const int which = blockIdx.y;
  const float* in = which == 0 ? a : which == 1 ? b : which == 2 ? c : d;
  u16* out       = which == 0 ? oa : which == 1 ? ob : which == 2 ? oc : od;
  int i = blockIdx.x * blockDim.x + threadIdx.x;
  int stride = gridDim.x * blockDim.x;
  for (int idx = i; idx < 262144; idx += stride) {
    float4 f = ((const float4*)in)[idx];
    ushort4 o = make_ushort4(f2bf(f.x), f2bf(f.y), f2bf(f.z), f2bf(f.w));
    ((ushort4*)out)[idx] = o;
  }
}

// ---------------- NT GEMM: out[m][n] = sum_k A[m][k]*W[n][k] + bias[n] ----------------
// 1D grid of 512 blocks, XCD-swizzled: 64 m-tiles x 8 n-tiles of 128.
// MODE 0: bf16 out row-major; MODE 1: bf16 out V-transposed (B,H,dk,S); MODE 2: f32 out.
template <int MODE>
__global__ __launch_bounds__(256, 2)
void gemm_bt(const u16* __restrict__ A, const u16* __restrict__ W,
             const float* __restrict__ bias, void* __restrict__ outp) {
  __shared__ u16 Alds[128 * 32];
  __shared__ u16 Blds[128 * 32];
  const int tid  = threadIdx.x;
  const int lane = tid & 63;
  const int wid  = tid >> 6;
  // XCD-aware swizzle: 512 wgs, 8 XCDs, 64 per XCD (contiguous m-rows per XCD)
  const int orig = blockIdx.x;
  const int swz  = (orig & 7) * 64 + (orig >> 3);
  const int m0 = (swz >> 3) * 128;
  const int n0 = (swz & 7) * 128;
  const int wm = (wid >> 1) * 64;
  const int wn = (wid & 1) * 64;

  f32x4 acc[4][4] = {};

  const int srow = tid >> 2;          // 0..63
  const int scol = (tid & 3) * 8;     // k-offset (elements)
  const u16* Ag = A + (size_t)(m0 + srow) * 1024 + scol;
  const u16* Wg = W + (size_t)(n0 + srow) * 1024 + scol;
  u16* Al = &Alds[wid * 16 * 32];     // wave-uniform LDS dest
  u16* Bl = &Blds[wid * 16 * 32];

  for (int k0 = 0; k0 < 1024; k0 += 32) {
    __syncthreads();
    gload_lds16(Ag + k0,             Al);
    gload_lds16(Ag + 64 * 1024 + k0, Al + 64 * 32);
    gload_lds16(Wg + k0,             Bl);
    gload_lds16(Wg + 64 * 1024 + k0, Bl + 64 * 32);
    __syncthreads();
    bf16x8 a[4], bb[4];
#pragma unroll
    for (int i = 0; i < 4; ++i)
      a[i] = *(const bf16x8*)&Alds[(wm + i * 16 + (lane & 15)) * 32 + (lane >> 4) * 8];
#pragma unroll
    for (int i = 0; i < 4; ++i)
      bb[i] = *(const bf16x8*)&Blds[(wn + i * 16 + (lane & 15)) * 32 + (lane >> 4) * 8];
#pragma unroll
    for (int mi = 0; mi < 4; ++mi)
#pragma unroll
      for (int ni = 0; ni < 4; ++ni)
        acc[mi][ni] = __builtin_amdgcn_mfma_f32_16x16x32_bf16(a[mi], bb[ni], acc[mi][ni], 0, 0, 0);
  }

  // epilogue: C/D layout col=lane&15, row=(lane>>4)*4+r
#pragma unroll
  for (int ni = 0; ni < 4; ++ni) {
    const int n = n0 + wn + ni * 16 + (lane & 15);
    const float bv = bias[n];
#pragma unroll
    for (int mi = 0; mi < 4; ++mi) {
      const int mBase = m0 + wm + mi * 16 + ((lane >> 4) << 2);
      if (MODE == 0) {
        u16* o = (u16*)outp;
#pragma unroll
        for (int r = 0; r < 4; ++r)
          o[(size_t)(mBase + r) * 1024 + n] = f2bf(acc[mi][ni][r] + bv);
      } else if (MODE == 2) {
        float* o = (float*)outp;
#pragma unroll
        for (int r = 0; r < 4; ++r)
          o[(size_t)(mBase + r) * 1024 + n] = acc[mi][ni][r] + bv;
      } else {
        u16* o = (u16*)outp;
        const int batch = mBase >> 9;
        const int s = mBase & 511;
        const int h = n >> 6;
        const int d = n & 63;
        ushort4 ov = make_ushort4(f2bf(acc[mi][ni][0] + bv), f2bf(acc[mi][ni][1] + bv),
                                  f2bf(acc[mi][ni][2] + bv), f2bf(acc[mi][ni][3] + bv));
        *(ushort4*)&o[((size_t)((batch * 16 + h) * 64 + d) << 9) + s] = ov;
      }
    }
  }
}

// ---------------- attention: one block per (b,h,qblock of 64 rows) ----------------
// Q,K: (B,S,D) bf16 ; Vt: (B,H,dk,S) bf16 ; rel: (1023,16) f32 ; Oa: (B,S,D) bf16
// 4 waves x 16 q-rows each, online softmax in-register, K/V tiles (128 keys)
// staged in LDS via global_load_lds with XOR-pre-swizzled source (T2+m173).
__global__ __launch_bounds__(256, 3)
void attn_kernel(const u16* __restrict__ Q, const u16* __restrict__ K,
                 const u16* __restrict__ Vt, const float* __restrict__ rel,
                 u16* __restrict__ Oa) {
  __shared__ u16 Kl[128 * 64];        // 16 KB: row=key, 64 d (128B rows, XOR-swz)
  __shared__ u16 Vl[64 * 128];        // 16 KB: row=d, 128 keys (256B rows, XOR-swz)
  __shared__ u16 Pl[4][16 * 136];     // 17.4 KB: per-wave P, stride 136 (16B-aligned)
  __shared__ float tcol[576];         // rel-bias slice

  const int tid  = threadIdx.x;
  const int lane = tid & 63;
  const int wid  = tid >> 6;
  const int g    = lane >> 4;         // 0..3
  const int lc   = lane & 15;

  // XCD swizzle: 2048 wgs = 8 XCDs x 256; q-blocks of one (b,h) contiguous per XCD
  const int orig = blockIdx.x;
  const int swz  = (orig & 7) * 256 + (orig >> 3);
  const int qb    = swz & 7;
  const int bh    = swz >> 3;
  const int h     = bh & 15;
  const int batch = bh >> 4;
  const int q0    = qb * 64;

  const size_t xbase  = (size_t)batch * 512 * 1024 + (size_t)h * 64;
  const size_t vtbase = (size_t)(batch * 16 + h) * 64 * 512;

  // rel-bias: bias(rowl,col) = tcol[rowl - col + 511], rowl in [0,64), col in [0,512)
  for (int u = tid; u < 575; u += 256)
    tcol[u] = rel[(size_t)(q0 + u) * 16 + h];

  // stage tile t: K rows = keys t*128.., V rows = d, cols = keys.
  // LDS dest is WAVE-UNIFORM base (HW adds lane*16B); source is XOR-pre-swizzled.
#define STAGE_TILE(t)                                                              \
  {                                                                                \
    _Pragma("unroll")                                                              \
    for (int j = 0; j < 4; ++j) {                                                  \
      const int kr = j * 32 + (tid >> 3);                                          \
      const int sk = (tid & 7) ^ (kr & 7);                                         \
      gload_lds16(K + xbase + (size_t)((t) * 128 + kr) * 1024 + sk * 8,            \
                  &Kl[j * 2048 + wid * 512]);                                      \
      const int vr = j * 16 + (tid >> 4);                                          \
      const int sv = (tid & 15) ^ (vr & 7);                                        \
      gload_lds16(Vt + vtbase + (size_t)vr * 512 + (t) * 128 + sv * 8,             \
                  &Vl[j * 2048 + wid * 512]);                                      \
    }                                                                              \
  }

  STAGE_TILE(0)

  // Q fragments: wave owns rows q0 + wid*16 + [0,16)
  bf16x8 aq[2];
#pragma unroll
  for (int ks = 0; ks < 2; ++ks)
    aq[ks] = *(const bf16x8*)&Q[xbase + (size_t)(q0 + wid * 16 + lc) * 1024 + ks * 32 + g * 8];

  float m_run[4], l_run[4];
  f32x4 acc_o[4] = {};
#pragma unroll
  for (int r = 0; r < 4; ++r) { m_run[r] = -1e30f; l_run[r] = 0.f; }

  __syncthreads();   // tile 0 + tcol ready

  const float scale = 0.125f;  // 1/sqrt(64)
  for (int t = 0; t < 4; ++t) {
    // ---- QK^T on 128-key tile (swizzled LDS reads) ----
    f32x4 acc[8] = {};
#pragma unroll
    for (int f = 0; f < 8; ++f) {
      const int rl = f * 16 + lc;
#pragma unroll
      for (int ks = 0; ks < 2; ++ks) {
        bf16x8 bk = *(const bf16x8*)&Kl[rl * 64 + (((ks * 4 + g) ^ (rl & 7)) * 8)];
        acc[f] = __builtin_amdgcn_mfma_f32_16x16x32_bf16(aq[ks], bk, acc[f], 0, 0, 0);
      }
    }
    // ---- scale + rel bias (rowl = wid*16+4g+r, col = t*128+f*16+lc) ----
    const int ubase = wid * 16 + 4 * g + 511 - t * 128 - lc;
#pragma unroll
    for (int f = 0; f < 8; ++f)
#pragma unroll
      for (int r = 0; r < 4; ++r)
        acc[f][r] = acc[f][r] * scale + tcol[ubase + r - f * 16];

    // ---- online softmax (within wave: in-reg over f, shfl over 16-lane group) ----
    float tm[4];
#pragma unroll
    for (int r = 0; r < 4; ++r) {
      float m = fmaxf(fmaxf(fmaxf(acc[0][r], acc[1][r]), fmaxf(acc[2][r], acc[3][r])),
                      fmaxf(fmaxf(acc[4][r], acc[5][r]), fmaxf(acc[6][r], acc[7][r])));
      m = fmaxf(m, __shfl_xor(m, 1));
      m = fmaxf(m, __shfl_xor(m, 2));
      m = fmaxf(m, __shfl_xor(m, 4));
      m = fmaxf(m, __shfl_xor(m, 8));
      tm[r] = m;
    }
    float al[4];
#pragma unroll
    for (int r = 0; r < 4; ++r) {
      const float mn = fmaxf(m_run[r], tm[r]);
      al[r] = __expf(m_run[r] - mn);
      m_run[r] = mn;
    }
    float ts[4] = {};
#pragma unroll
    for (int f = 0; f < 8; ++f)
#pragma unroll
      for (int r = 0; r < 4; ++r) {
        const float e = __expf(acc[f][r] - m_run[r]);
        ts[r] += e;
        Pl[wid][(4 * g + r) * 136 + f * 16 + lc] = f2bf(e);
      }
#pragma unroll
    for (int r = 0; r < 4; ++r) {
      float s = ts[r];
      s += __shfl_xor(s, 1);
      s += __shfl_xor(s, 2);
      s += __shfl_xor(s, 4);
      s += __shfl_xor(s, 8);
      l_run[r] = l_run[r] * al[r] + s;
    }
#pragma unroll
    for (int dblk = 0; dblk < 4; ++dblk)
#pragma unroll
      for (int r = 0; r < 4; ++r)
        acc_o[dblk][r] *= al[r];

    // ---- PV: A = P (per-wave LDS slab), B = V tile (swizzled LDS) ----
#pragma unroll
    for (int ks = 0; ks < 4; ++ks) {
      bf16x8 ap = *(const bf16x8*)&Pl[wid][lc * 136 + ks * 32 + g * 8];
#pragma unroll
      for (int dblk = 0; dblk < 4; ++dblk) {
        const int dr = dblk * 16 + lc;
        bf16x8 bv = *(const bf16x8*)&Vl[dr * 128 + (((ks * 4 + g) ^ (dr & 7)) * 8)];
        acc_o[dblk] = __builtin_amdgcn_mfma_f32_16x16x32_bf16(ap, bv, acc_o[dblk], 0, 0, 0);
      }
    }

    if (t < 3) {
      __syncthreads();          // all waves done with tile t
      STAGE_TILE(t + 1)
      __syncthreads();          // tile t+1 landed (barrier drains vmcnt)
    }
  }
#undef STAGE_TILE

  // ---- epilogue ----
#pragma unroll
  for (int dblk = 0; dblk < 4; ++dblk)
#pragma unroll
    for (int r = 0; r < 4; ++r) {
      const int row = q0 + wid * 16 + 4 * g + r;
      Oa[((size_t)batch * 512 + row) * 1024 + h * 64 + dblk * 16 + lc] =
          f2bf(acc_o[dblk][r] / l_run[r]);
    }
}

// ---------------- launch ----------------
extern "C" void kernel_launch(void* const* d_in, const int* in_sizes, int n_in,
                              void* d_out, int out_size, void* d_ws, size_t ws_size,
                              hipStream_t stream) {
  (void)in_sizes; (void)n_in; (void)out_size; (void)ws_size;
  const float* x   = (const float*)d_in[0];
  const float* Wq  = (const float*)d_in[1];
  const float* bq  = (const float*)d_in[2];
  const float* Wk  = (const float*)d_in[3];
  const float* bk  = (const float*)d_in[4];
  const float* Wv  = (const float*)d_in[5];
  const float* bv  = (const float*)d_in[6];
  const float* Wo  = (const float*)d_in[7];
  const float* bo  = (const float*)d_in[8];
  const float* rel = (const float*)d_in[9];
  float* out = (float*)d_out;

  u16* p = (u16*)d_ws;
  u16* xbf = p;  p += (size_t)8192 * 1024;
  u16* wqb = p;  p += (size_t)1024 * 1024;
  u16* wkb = p;  p += (size_t)1024 * 1024;
  u16* wvb = p;  p += (size_t)1024 * 1024;
  u16* wob = p;  p += (size_t)1024 * 1024;
  u16* qbf = p;  p += (size_t)8192 * 1024;
  u16* kbf = p;  p += (size_t)8192 * 1024;
  u16* vtb = p;  p += (size_t)8192 * 1024;
  u16* abf = p;  p += (size_t)8192 * 1024;

  cast_bf16_kernel<<<1024, 256, 0, stream>>>(x, xbf, 8192 * 1024 / 4);
  cast_w4_kernel<<<dim3(256, 4), 256, 0, stream>>>(Wq, Wk, Wv, Wo, wqb, wkb, wvb, wob);

  gemm_bt<0><<<512, 256, 0, stream>>>(xbf, wqb, bq, qbf);
  gemm_bt<0><<<512, 256, 0, stream>>>(xbf, wkb, bk, kbf);
  gemm_bt<1><<<512, 256, 0, stream>>>(xbf, wvb, bv, vtb);

  attn_kernel<<<2048, 256, 0, stream>>>(qbf, kbf, vtb, rel, abf);

  gemm_bt<2><<<512, 256, 0, stream>>>(abf, wob, bo, out);
}

// Round 5
// 248.388 us; speedup vs baseline: 1.5212x; 1.0449x over previous
//
#include <hip/hip_runtime.h>
#include <cstdint>
#include <cstddef>

typedef unsigned short u16;
typedef __attribute__((ext_vector_type(8))) short bf16x8;   // 8 bf16 = 4 VGPRs
typedef __attribute__((ext_vector_type(4))) float f32x4;

__device__ __forceinline__ u16 f2bf(float f) {
  unsigned u = __builtin_bit_cast(unsigned, f);
  return (u16)((u + 0x7FFFu + ((u >> 16) & 1u)) >> 16);   // RNE
}

__device__ __forceinline__ void gload_lds16(const void* g, void* l) {
  __builtin_amdgcn_global_load_lds(
      (const __attribute__((address_space(1))) void*)g,
      (__attribute__((address_space(3))) void*)l,
      16, 0, 0);
}

// ---------------- merged cast fp32 -> bf16 (x + 4 weights, one launch) ----------------
__global__ void cast_all_kernel(const float* __restrict__ x,
                                const float* __restrict__ wq, const float* __restrict__ wk,
                                const float* __restrict__ wv, const float* __restrict__ wo,
                                u16* __restrict__ ox,
                                u16* __restrict__ oq, u16* __restrict__ ok,
                                u16* __restrict__ ov, u16* __restrict__ oo) {
  const int which = blockIdx.y;
  const float* in = which == 0 ? x  : which == 1 ? wq : which == 2 ? wk
                                    : which == 3 ? wv : wo;
  u16* out        = which == 0 ? ox : which == 1 ? oq : which == 2 ? ok
                                    : which == 3 ? ov : oo;
  const int n4 = which == 0 ? 8192 * 1024 / 4 : 262144;
  int i = blockIdx.x * blockDim.x + threadIdx.x;
  int stride = gridDim.x * blockDim.x;
  for (int idx = i; idx < n4; idx += stride) {
    float4 f = ((const float4*)in)[idx];
    ushort4 o = make_ushort4(f2bf(f.x), f2bf(f.y), f2bf(f.z), f2bf(f.w));
    ((ushort4*)out)[idx] = o;
  }
}

// ---------------- fused QKV GEMM: A (8192x1024) x W_qkv^T (3072x1024) ----------------
// Output routing per 1024-wide n-region: Q row-major, K row-major, V transposed (B,H,dk,S).
// 1536 blocks = 64 m-tiles x 24 n-tiles of 128, XCD-swizzled (1536 = 8 x 192).
__global__ __launch_bounds__(256, 2)
void gemm_qkv(const u16* __restrict__ A, const u16* __restrict__ W,
              const float* __restrict__ bq, const float* __restrict__ bk,
              const float* __restrict__ bvv,
              u16* __restrict__ qout, u16* __restrict__ kout, u16* __restrict__ vt) {
  __shared__ u16 Alds[128 * 32];
  __shared__ u16 Blds[128 * 32];
  const int tid  = threadIdx.x;
  const int lane = tid & 63;
  const int wid  = tid >> 6;
  const int orig = blockIdx.x;
  const int swz  = (orig & 7) * 192 + (orig >> 3);
  const int m0 = (swz / 24) * 128;
  const int n0 = (swz % 24) * 128;
  const int wm = (wid >> 1) * 64;
  const int wn = (wid & 1) * 64;

  f32x4 acc[4][4] = {};

  const int srow = tid >> 2;
  const int scol = (tid & 3) * 8;
  const u16* Ag = A + (size_t)(m0 + srow) * 1024 + scol;
  const u16* Wg = W + (size_t)(n0 + srow) * 1024 + scol;
  u16* Al = &Alds[wid * 16 * 32];
  u16* Bl = &Blds[wid * 16 * 32];

  for (int k0 = 0; k0 < 1024; k0 += 32) {
    __syncthreads();
    gload_lds16(Ag + k0,             Al);
    gload_lds16(Ag + 64 * 1024 + k0, Al + 64 * 32);
    gload_lds16(Wg + k0,             Bl);
    gload_lds16(Wg + 64 * 1024 + k0, Bl + 64 * 32);
    __syncthreads();
    bf16x8 a[4], bb[4];
#pragma unroll
    for (int i = 0; i < 4; ++i)
      a[i] = *(const bf16x8*)&Alds[(wm + i * 16 + (lane & 15)) * 32 + (lane >> 4) * 8];
#pragma unroll
    for (int i = 0; i < 4; ++i)
      bb[i] = *(const bf16x8*)&Blds[(wn + i * 16 + (lane & 15)) * 32 + (lane >> 4) * 8];
#pragma unroll
    for (int mi = 0; mi < 4; ++mi)
#pragma unroll
      for (int ni = 0; ni < 4; ++ni)
        acc[mi][ni] = __builtin_amdgcn_mfma_f32_16x16x32_bf16(a[mi], bb[ni], acc[mi][ni], 0, 0, 0);
  }

  const int region = n0 >> 10;   // 0=Q, 1=K, 2=V (n-tile 128-aligned -> uniform per block)
#pragma unroll
  for (int ni = 0; ni < 4; ++ni) {
    const int n  = n0 + wn + ni * 16 + (lane & 15);
    const int nn = n & 1023;
    const float bias = region == 0 ? bq[nn] : region == 1 ? bk[nn] : bvv[nn];
#pragma unroll
    for (int mi = 0; mi < 4; ++mi) {
      const int mBase = m0 + wm + mi * 16 + ((lane >> 4) << 2);
      if (region == 0) {
#pragma unroll
        for (int r = 0; r < 4; ++r)
          qout[(size_t)(mBase + r) * 1024 + nn] = f2bf(acc[mi][ni][r] + bias);
      } else if (region == 1) {
#pragma unroll
        for (int r = 0; r < 4; ++r)
          kout[(size_t)(mBase + r) * 1024 + nn] = f2bf(acc[mi][ni][r] + bias);
      } else {
        // V transposed: vt[((batch*16 + h)*64 + d)*512 + s]
        const int batch = mBase >> 9;
        const int s = mBase & 511;
        const int h = nn >> 6;
        const int d = nn & 63;
        ushort4 ov = make_ushort4(f2bf(acc[mi][ni][0] + bias), f2bf(acc[mi][ni][1] + bias),
                                  f2bf(acc[mi][ni][2] + bias), f2bf(acc[mi][ni][3] + bias));
        *(ushort4*)&vt[((size_t)((batch * 16 + h) * 64 + d) << 9) + s] = ov;
      }
    }
  }
}

// ---------------- O-projection GEMM: out[m][n] = sum_k A[m][k]*W[n][k] + bias[n], f32 out ----
__global__ __launch_bounds__(256, 2)
void gemm_out(const u16* __restrict__ A, const u16* __restrict__ W,
              const float* __restrict__ bias, float* __restrict__ outp) {
  __shared__ u16 Alds[128 * 32];
  __shared__ u16 Blds[128 * 32];
  const int tid  = threadIdx.x;
  const int lane = tid & 63;
  const int wid  = tid >> 6;
  const int orig = blockIdx.x;
  const int swz  = (orig & 7) * 64 + (orig >> 3);
  const int m0 = (swz >> 3) * 128;
  const int n0 = (swz & 7) * 128;
  const int wm = (wid >> 1) * 64;
  const int wn = (wid & 1) * 64;

  f32x4 acc[4][4] = {};

  const int srow = tid >> 2;
  const int scol = (tid & 3) * 8;
  const u16* Ag = A + (size_t)(m0 + srow) * 1024 + scol;
  const u16* Wg = W + (size_t)(n0 + srow) * 1024 + scol;
  u16* Al = &Alds[wid * 16 * 32];
  u16* Bl = &Blds[wid * 16 * 32];

  for (int k0 = 0; k0 < 1024; k0 += 32) {
    __syncthreads();
    gload_lds16(Ag + k0,             Al);
    gload_lds16(Ag + 64 * 1024 + k0, Al + 64 * 32);
    gload_lds16(Wg + k0,             Bl);
    gload_lds16(Wg + 64 * 1024 + k0, Bl + 64 * 32);
    __syncthreads();
    bf16x8 a[4], bb[4];
#pragma unroll
    for (int i = 0; i < 4; ++i)
      a[i] = *(const bf16x8*)&Alds[(wm + i * 16 + (lane & 15)) * 32 + (lane >> 4) * 8];
#pragma unroll
    for (int i = 0; i < 4; ++i)
      bb[i] = *(const bf16x8*)&Blds[(wn + i * 16 + (lane & 15)) * 32 + (lane >> 4) * 8];
#pragma unroll
    for (int mi = 0; mi < 4; ++mi)
#pragma unroll
      for (int ni = 0; ni < 4; ++ni)
        acc[mi][ni] = __builtin_amdgcn_mfma_f32_16x16x32_bf16(a[mi], bb[ni], acc[mi][ni], 0, 0, 0);
  }

#pragma unroll
  for (int ni = 0; ni < 4; ++ni) {
    const int n = n0 + wn + ni * 16 + (lane & 15);
    const float bv = bias[n];
#pragma unroll
    for (int mi = 0; mi < 4; ++mi) {
      const int mBase = m0 + wm + mi * 16 + ((lane >> 4) << 2);
#pragma unroll
      for (int r = 0; r < 4; ++r)
        outp[(size_t)(mBase + r) * 1024 + n] = acc[mi][ni][r] + bv;
    }
  }
}

// ---------------- attention: one block per (b,h,qblock of 64 rows) ----------------
__global__ __launch_bounds__(256, 3)
void attn_kernel(const u16* __restrict__ Q, const u16* __restrict__ K,
                 const u16* __restrict__ Vt, const float* __restrict__ rel,
                 u16* __restrict__ Oa) {
  __shared__ u16 Kl[128 * 64];        // 16 KB: row=key, 64 d (128B rows, XOR-swz)
  __shared__ u16 Vl[64 * 128];        // 16 KB: row=d, 128 keys (256B rows, XOR-swz)
  __shared__ u16 Pl[4][16 * 136];     // 17.4 KB: per-wave P, stride 136 (16B-aligned)
  __shared__ float tcol[576];         // rel-bias slice

  const int tid  = threadIdx.x;
  const int lane = tid & 63;
  const int wid  = tid >> 6;
  const int g    = lane >> 4;         // 0..3
  const int lc   = lane & 15;

  const int orig = blockIdx.x;
  const int swz  = (orig & 7) * 256 + (orig >> 3);
  const int qb    = swz & 7;
  const int bh    = swz >> 3;
  const int h     = bh & 15;
  const int batch = bh >> 4;
  const int q0    = qb * 64;

  const size_t xbase  = (size_t)batch * 512 * 1024 + (size_t)h * 64;
  const size_t vtbase = (size_t)(batch * 16 + h) * 64 * 512;

  for (int u = tid; u < 575; u += 256)
    tcol[u] = rel[(size_t)(q0 + u) * 16 + h];

#define STAGE_TILE(t)                                                              \
  {                                                                                \
    _Pragma("unroll")                                                              \
    for (int j = 0; j < 4; ++j) {                                                  \
      const int kr = j * 32 + (tid >> 3);                                          \
      const int sk = (tid & 7) ^ (kr & 7);                                         \
      gload_lds16(K + xbase + (size_t)((t) * 128 + kr) * 1024 + sk * 8,            \
                  &Kl[j * 2048 + wid * 512]);                                      \
      const int vr = j * 16 + (tid >> 4);                                          \
      const int sv = (tid & 15) ^ (vr & 7);                                        \
      gload_lds16(Vt + vtbase + (size_t)vr * 512 + (t) * 128 + sv * 8,             \
                  &Vl[j * 2048 + wid * 512]);                                      \
    }                                                                              \
  }

  STAGE_TILE(0)

  bf16x8 aq[2];
#pragma unroll
  for (int ks = 0; ks < 2; ++ks)
    aq[ks] = *(const bf16x8*)&Q[xbase + (size_t)(q0 + wid * 16 + lc) * 1024 + ks * 32 + g * 8];

  float m_run[4], l_run[4];
  f32x4 acc_o[4] = {};
#pragma unroll
  for (int r = 0; r < 4; ++r) { m_run[r] = -1e30f; l_run[r] = 0.f; }

  __syncthreads();   // tile 0 + tcol ready

  const float scale = 0.125f;  // 1/sqrt(64)
  for (int t = 0; t < 4; ++t) {
    f32x4 acc[8] = {};
#pragma unroll
    for (int f = 0; f < 8; ++f) {
      const int rl = f * 16 + lc;
#pragma unroll
      for (int ks = 0; ks < 2; ++ks) {
        bf16x8 bk = *(const bf16x8*)&Kl[rl * 64 + (((ks * 4 + g) ^ (rl & 7)) * 8)];
        acc[f] = __builtin_amdgcn_mfma_f32_16x16x32_bf16(aq[ks], bk, acc[f], 0, 0, 0);
      }
    }
    const int ubase = wid * 16 + 4 * g + 511 - t * 128 - lc;
#pragma unroll
    for (int f = 0; f < 8; ++f)
#pragma unroll
      for (int r = 0; r < 4; ++r)
        acc[f][r] = acc[f][r] * scale + tcol[ubase + r - f * 16];

    float tm[4];
#pragma unroll
    for (int r = 0; r < 4; ++r) {
      float m = fmaxf(fmaxf(fmaxf(acc[0][r], acc[1][r]), fmaxf(acc[2][r], acc[3][r])),
                      fmaxf(fmaxf(acc[4][r], acc[5][r]), fmaxf(acc[6][r], acc[7][r])));
      m = fmaxf(m, __shfl_xor(m, 1));
      m = fmaxf(m, __shfl_xor(m, 2));
      m = fmaxf(m, __shfl_xor(m, 4));
      m = fmaxf(m, __shfl_xor(m, 8));
      tm[r] = m;
    }
    float al[4];
#pragma unroll
    for (int r = 0; r < 4; ++r) {
      const float mn = fmaxf(m_run[r], tm[r]);
      al[r] = __expf(m_run[r] - mn);
      m_run[r] = mn;
    }
    float ts[4] = {};
#pragma unroll
    for (int f = 0; f < 8; ++f)
#pragma unroll
      for (int r = 0; r < 4; ++r) {
        const float e = __expf(acc[f][r] - m_run[r]);
        ts[r] += e;
        Pl[wid][(4 * g + r) * 136 + f * 16 + lc] = f2bf(e);
      }
#pragma unroll
    for (int r = 0; r < 4; ++r) {
      float s = ts[r];
      s += __shfl_xor(s, 1);
      s += __shfl_xor(s, 2);
      s += __shfl_xor(s, 4);
      s += __shfl_xor(s, 8);
      l_run[r] = l_run[r] * al[r] + s;
    }
#pragma unroll
    for (int dblk = 0; dblk < 4; ++dblk)
#pragma unroll
      for (int r = 0; r < 4; ++r)
        acc_o[dblk][r] *= al[r];

#pragma unroll
    for (int ks = 0; ks < 4; ++ks) {
      bf16x8 ap = *(const bf16x8*)&Pl[wid][lc * 136 + ks * 32 + g * 8];
#pragma unroll
      for (int dblk = 0; dblk < 4; ++dblk) {
        const int dr = dblk * 16 + lc;
        bf16x8 bv = *(const bf16x8*)&Vl[dr * 128 + (((ks * 4 + g) ^ (dr & 7)) * 8)];
        acc_o[dblk] = __builtin_amdgcn_mfma_f32_16x16x32_bf16(ap, bv, acc_o[dblk], 0, 0, 0);
      }
    }

    if (t < 3) {
      __syncthreads();
      STAGE_TILE(t + 1)
      __syncthreads();
    }
  }
#undef STAGE_TILE

#pragma unroll
  for (int dblk = 0; dblk < 4; ++dblk)
#pragma unroll
    for (int r = 0; r < 4; ++r) {
      const int row = q0 + wid * 16 + 4 * g + r;
      Oa[((size_t)batch * 512 + row) * 1024 + h * 64 + dblk * 16 + lc] =
          f2bf(acc_o[dblk][r] / l_run[r]);
    }
}

// ---------------- launch ----------------
extern "C" void kernel_launch(void* const* d_in, const int* in_sizes, int n_in,
                              void* d_out, int out_size, void* d_ws, size_t ws_size,
                              hipStream_t stream) {
  (void)in_sizes; (void)n_in; (void)out_size; (void)ws_size;
  const float* x   = (const float*)d_in[0];
  const float* Wq  = (const float*)d_in[1];
  const float* bq  = (const float*)d_in[2];
  const float* Wk  = (const float*)d_in[3];
  const float* bk  = (const float*)d_in[4];
  const float* Wv  = (const float*)d_in[5];
  const float* bv  = (const float*)d_in[6];
  const float* Wo  = (const float*)d_in[7];
  const float* bo  = (const float*)d_in[8];
  const float* rel = (const float*)d_in[9];
  float* out = (float*)d_out;

  u16* p = (u16*)d_ws;
  u16* xbf = p;  p += (size_t)8192 * 1024;
  u16* wqb = p;  p += (size_t)1024 * 1024;   // wq, wk, wv contiguous => fused 3072x1024
  u16* wkb = p;  p += (size_t)1024 * 1024;
  u16* wvb = p;  p += (size_t)1024 * 1024;
  u16* wob = p;  p += (size_t)1024 * 1024;
  u16* qbf = p;  p += (size_t)8192 * 1024;
  u16* kbf = p;  p += (size_t)8192 * 1024;
  u16* vtb = p;  p += (size_t)8192 * 1024;
  u16* abf = p;  p += (size_t)8192 * 1024;

  cast_all_kernel<<<dim3(1024, 5), 256, 0, stream>>>(x, Wq, Wk, Wv, Wo,
                                                     xbf, wqb, wkb, wvb, wob);

  gemm_qkv<<<1536, 256, 0, stream>>>(xbf, wqb, bq, bk, bv, qbf, kbf, vtb);

  attn_kernel<<<2048, 256, 0, stream>>>(qbf, kbf, vtb, rel, abf);

  gemm_out<<<512, 256, 0, stream>>>(abf, wob, bo, out);
}